// Round 16
// baseline (59.923 us; speedup 1.0000x reference)
//
#include <hip/hip_runtime.h>

// Depthwise 7x7 'same' conv, fp32 in/out. B=16, C=256, H=W=64.
// R14 EXACTLY (verified best, 32.0us: wave = half-plane, lane = 4w x 8h
// tile, 32 f32 acc, dot2 inner product, distance-5 dataflow load
// pipeline; 15 outstanding dwordx4/wave). ONLY change vs R14:
// __launch_bounds__(256,2) -> (256,4), capping VGPR at 128 so 4 waves
// fit per SIMD. Live state ~122 VGPR (5 live slots x 12 + 32 acc + ~30
// working) should fit 128 WITHOUT spill -> +33% TLP and +33% MLP/SIMD
// (60 outstanding loads/SIMD) against the L3-flushed ~900cy HBM miss.
// Spill tripwire: FETCH/WRITE ballooning +100MB (R3 signature).

typedef _Float16 v2h __attribute__((ext_vector_type(2)));

static __device__ __forceinline__ v2h pack2(float a, float b) {
    return __builtin_bit_cast(v2h, __builtin_amdgcn_cvt_pkrtz(a, b));
}

__global__ __launch_bounds__(256, 4)
void dwconv7x7_dist5o(const float* __restrict__ x,
                      const float* __restrict__ weight,
                      const float* __restrict__ bias,
                      float* __restrict__ out) {
    const int tid  = threadIdx.x;
    const int lane = tid & 63;
    const int wid  = tid >> 6;
    const int gw   = blockIdx.x * 4 + wid;   // 0..8191
    const int plane = gw >> 1;               // b*256 + c
    const int half  = gw & 1;
    const int c = __builtin_amdgcn_readfirstlane(plane & 255);

    // ---- per-channel weights (uniform): half2 pairs in SGPRs ----
    const float* wp = weight + c * 49;
    float wk[49];
#pragma unroll
    for (int k = 0; k < 49; ++k) wk[k] = wp[k];
    const float bv = bias[c];

    v2h  W[7][3];     // taps (0,1),(2,3),(4,5) per kernel row
    float w6[7];      // tap 6 scalar
#pragma unroll
    for (int kr = 0; kr < 7; ++kr) {
#pragma unroll
        for (int t = 0; t < 3; ++t) {
            v2h p = pack2(wk[kr * 7 + 2 * t], wk[kr * 7 + 2 * t + 1]);
            int b = __builtin_amdgcn_readfirstlane(__builtin_bit_cast(int, p));
            W[kr][t] = __builtin_bit_cast(v2h, b);
        }
        w6[kr] = wk[kr * 7 + 6];
    }

    const int tx = lane & 15;        // 16 tiles across width
    const int sy = lane >> 4;        // 4 strips per half-plane
    const int wb = tx * 4;           // output col base
    const int hb = half * 32 + sy * 8;

    const float* xp = x + (size_t)plane * 4096;
    const int offm = (tx > 0)  ? (wb - 4) : wb;   // clamped aligned left
    const int offp = (tx < 15) ? (wb + 4) : wb;   // clamped aligned right

    float acc[8][4];
#pragma unroll
    for (int i = 0; i < 8; ++i)
#pragma unroll
        for (int j = 0; j < 4; ++j) acc[i][j] = 0.f;

    // load pipeline: L[j] holds row (hb-3+j)'s 3 dwordx4. All indices
    // become compile-time constants after unrolling -> register-promoted;
    // liveness (5 slots live at a time) keeps it ~60 VGPR.
    float4 L[14][3];

#define ISSUE(J) do {                                              \
        const int rr_ = min(max(hb - 3 + (J), 0), 63);             \
        const float* rowp_ = xp + rr_ * 64;                        \
        L[J][0] = *reinterpret_cast<const float4*>(rowp_ + offm);  \
        L[J][1] = *reinterpret_cast<const float4*>(rowp_ + wb);    \
        L[J][2] = *reinterpret_cast<const float4*>(rowp_ + offp);  \
    } while (0)

    // prologue: rows 0..4 in flight (15 loads)
#pragma unroll
    for (int j = 0; j < 5; ++j) ISSUE(j);

#pragma unroll
    for (int j = 0; j < 14; ++j) {
        const int r = hb - 3 + j;
        const bool mrow = (r >= 0) && (r < 64);
        const bool mm = mrow && (tx > 0);
        const bool mp = mrow && (tx < 15);

        // f[i] = x[r][wb-3+i], i = 0..9 (masked to zero outside)
        float f[10];
        f[0] = mm   ? L[j][0].y : 0.f;
        f[1] = mm   ? L[j][0].z : 0.f;
        f[2] = mm   ? L[j][0].w : 0.f;
        f[3] = mrow ? L[j][1].x : 0.f;
        f[4] = mrow ? L[j][1].y : 0.f;
        f[5] = mrow ? L[j][1].z : 0.f;
        f[6] = mrow ? L[j][1].w : 0.f;
        f[7] = mp   ? L[j][2].x : 0.f;
        f[8] = mp   ? L[j][2].y : 0.f;
        f[9] = mp   ? L[j][2].z : 0.f;

        // keep the pipeline 5 ahead
        if (j + 5 < 14) ISSUE(j + 5);

        // sliding half2 pairs: pk[t] = (f[t], f[t+1])
        v2h pk[8];
#pragma unroll
        for (int t = 0; t < 8; ++t) pk[t] = pack2(f[t], f[t + 1]);

        // output row oi (kr = j - oi), col wb+jj: taps -> f[jj+kc]
#pragma unroll
        for (int oi = 0; oi < 8; ++oi) {
            const int kr = j - oi;
            if (kr >= 0 && kr < 7) {
#pragma unroll
                for (int jj = 0; jj < 4; ++jj) {
                    float a = fmaf(f[jj + 6], w6[kr], acc[oi][jj]);
                    a = __builtin_amdgcn_fdot2(pk[jj + 4], W[kr][2], a, false);
                    a = __builtin_amdgcn_fdot2(pk[jj + 2], W[kr][1], a, false);
                    a = __builtin_amdgcn_fdot2(pk[jj],     W[kr][0], a, false);
                    acc[oi][jj] = a;
                }
            }
        }
    }
#undef ISSUE

    // ---- write 8 rows x float4, plus bias ----
    float* op = out + (size_t)plane * 4096 + (size_t)hb * 64 + wb;
#pragma unroll
    for (int oi = 0; oi < 8; ++oi) {
        float4 v;
        v.x = acc[oi][0] + bv;
        v.y = acc[oi][1] + bv;
        v.z = acc[oi][2] + bv;
        v.w = acc[oi][3] + bv;
        *reinterpret_cast<float4*>(op + oi * 64) = v;
    }
}

extern "C" void kernel_launch(void* const* d_in, const int* in_sizes, int n_in,
                              void* d_out, int out_size, void* d_ws, size_t ws_size,
                              hipStream_t stream) {
    const float* x      = (const float*)d_in[0];
    const float* weight = (const float*)d_in[1];
    const float* bias   = (const float*)d_in[2];
    float* out          = (float*)d_out;
    (void)in_sizes; (void)n_in; (void)out_size; (void)d_ws; (void)ws_size;

    // 8192 waves = 2048 blocks x 256 threads (4 waves/block)
    dim3 grid(2048);
    dim3 block(256);
    dwconv7x7_dist5o<<<grid, block, 0, stream>>>(x, weight, bias, out);
}

// Round 17
// 32.520 us; speedup vs baseline: 1.8426x; 1.8426x over previous
//
#include <hip/hip_runtime.h>

// Depthwise 7x7 'same' conv, fp32 in/out. B=16, C=256, H=W=64.
// R14 EXACTLY (verified best, 32.0us: wave = half-plane, lane = 4w x 8h
// tile, 32 f32 acc, dot2 inner product, distance-5 dataflow load
// pipeline; 15 outstanding dwordx4/wave). ONLY change vs R14:
// __launch_bounds__(256,2) -> (256,3): VGPR cap ~168.
// R16 taught: cap 128 doesn't fit dist-5's live set (allocator bailed to
// 64 VGPR + scratch: FETCH 100MB/WRITE 172MB). Cap 256 (R14) likely
// allocated >170 -> only 2 waves/SIMD. Cap 168 targets the middle:
// live set ~135-160 fits -> 3 waves/SIMD, +50% TLP, 45 outstanding
// loads/SIMD vs 30, against the L3-flushed ~900cy HBM miss.

typedef _Float16 v2h __attribute__((ext_vector_type(2)));

static __device__ __forceinline__ v2h pack2(float a, float b) {
    return __builtin_bit_cast(v2h, __builtin_amdgcn_cvt_pkrtz(a, b));
}

__global__ __launch_bounds__(256, 3)
void dwconv7x7_dist5m(const float* __restrict__ x,
                      const float* __restrict__ weight,
                      const float* __restrict__ bias,
                      float* __restrict__ out) {
    const int tid  = threadIdx.x;
    const int lane = tid & 63;
    const int wid  = tid >> 6;
    const int gw   = blockIdx.x * 4 + wid;   // 0..8191
    const int plane = gw >> 1;               // b*256 + c
    const int half  = gw & 1;
    const int c = __builtin_amdgcn_readfirstlane(plane & 255);

    // ---- per-channel weights (uniform): half2 pairs in SGPRs ----
    const float* wp = weight + c * 49;
    float wk[49];
#pragma unroll
    for (int k = 0; k < 49; ++k) wk[k] = wp[k];
    const float bv = bias[c];

    v2h  W[7][3];     // taps (0,1),(2,3),(4,5) per kernel row
    float w6[7];      // tap 6 scalar
#pragma unroll
    for (int kr = 0; kr < 7; ++kr) {
#pragma unroll
        for (int t = 0; t < 3; ++t) {
            v2h p = pack2(wk[kr * 7 + 2 * t], wk[kr * 7 + 2 * t + 1]);
            int b = __builtin_amdgcn_readfirstlane(__builtin_bit_cast(int, p));
            W[kr][t] = __builtin_bit_cast(v2h, b);
        }
        w6[kr] = wk[kr * 7 + 6];
    }

    const int tx = lane & 15;        // 16 tiles across width
    const int sy = lane >> 4;        // 4 strips per half-plane
    const int wb = tx * 4;           // output col base
    const int hb = half * 32 + sy * 8;

    const float* xp = x + (size_t)plane * 4096;
    const int offm = (tx > 0)  ? (wb - 4) : wb;   // clamped aligned left
    const int offp = (tx < 15) ? (wb + 4) : wb;   // clamped aligned right

    float acc[8][4];
#pragma unroll
    for (int i = 0; i < 8; ++i)
#pragma unroll
        for (int j = 0; j < 4; ++j) acc[i][j] = 0.f;

    // load pipeline: L[j] holds row (hb-3+j)'s 3 dwordx4. All indices
    // become compile-time constants after unrolling -> register-promoted;
    // liveness (5 slots at a time) ~60 VGPR.
    float4 L[14][3];

#define ISSUE(J) do {                                              \
        const int rr_ = min(max(hb - 3 + (J), 0), 63);             \
        const float* rowp_ = xp + rr_ * 64;                        \
        L[J][0] = *reinterpret_cast<const float4*>(rowp_ + offm);  \
        L[J][1] = *reinterpret_cast<const float4*>(rowp_ + wb);    \
        L[J][2] = *reinterpret_cast<const float4*>(rowp_ + offp);  \
    } while (0)

    // prologue: rows 0..4 in flight (15 loads)
#pragma unroll
    for (int j = 0; j < 5; ++j) ISSUE(j);

#pragma unroll
    for (int j = 0; j < 14; ++j) {
        const int r = hb - 3 + j;
        const bool mrow = (r >= 0) && (r < 64);
        const bool mm = mrow && (tx > 0);
        const bool mp = mrow && (tx < 15);

        // f[i] = x[r][wb-3+i], i = 0..9 (masked to zero outside)
        float f[10];
        f[0] = mm   ? L[j][0].y : 0.f;
        f[1] = mm   ? L[j][0].z : 0.f;
        f[2] = mm   ? L[j][0].w : 0.f;
        f[3] = mrow ? L[j][1].x : 0.f;
        f[4] = mrow ? L[j][1].y : 0.f;
        f[5] = mrow ? L[j][1].z : 0.f;
        f[6] = mrow ? L[j][1].w : 0.f;
        f[7] = mp   ? L[j][2].x : 0.f;
        f[8] = mp   ? L[j][2].y : 0.f;
        f[9] = mp   ? L[j][2].z : 0.f;

        // keep the pipeline 5 ahead
        if (j + 5 < 14) ISSUE(j + 5);

        // sliding half2 pairs: pk[t] = (f[t], f[t+1])
        v2h pk[8];
#pragma unroll
        for (int t = 0; t < 8; ++t) pk[t] = pack2(f[t], f[t + 1]);

        // output row oi (kr = j - oi), col wb+jj: taps -> f[jj+kc]
#pragma unroll
        for (int oi = 0; oi < 8; ++oi) {
            const int kr = j - oi;
            if (kr >= 0 && kr < 7) {
#pragma unroll
                for (int jj = 0; jj < 4; ++jj) {
                    float a = fmaf(f[jj + 6], w6[kr], acc[oi][jj]);
                    a = __builtin_amdgcn_fdot2(pk[jj + 4], W[kr][2], a, false);
                    a = __builtin_amdgcn_fdot2(pk[jj + 2], W[kr][1], a, false);
                    a = __builtin_amdgcn_fdot2(pk[jj],     W[kr][0], a, false);
                    acc[oi][jj] = a;
                }
            }
        }
    }
#undef ISSUE

    // ---- write 8 rows x float4, plus bias ----
    float* op = out + (size_t)plane * 4096 + (size_t)hb * 64 + wb;
#pragma unroll
    for (int oi = 0; oi < 8; ++oi) {
        float4 v;
        v.x = acc[oi][0] + bv;
        v.y = acc[oi][1] + bv;
        v.z = acc[oi][2] + bv;
        v.w = acc[oi][3] + bv;
        *reinterpret_cast<float4*>(op + oi * 64) = v;
    }
}

extern "C" void kernel_launch(void* const* d_in, const int* in_sizes, int n_in,
                              void* d_out, int out_size, void* d_ws, size_t ws_size,
                              hipStream_t stream) {
    const float* x      = (const float*)d_in[0];
    const float* weight = (const float*)d_in[1];
    const float* bias   = (const float*)d_in[2];
    float* out          = (float*)d_out;
    (void)in_sizes; (void)n_in; (void)out_size; (void)d_ws; (void)ws_size;

    // 8192 waves = 2048 blocks x 256 threads (4 waves/block)
    dim3 grid(2048);
    dim3 block(256);
    dwconv7x7_dist5m<<<grid, block, 0, stream>>>(x, weight, bias, out);
}